// Round 1
// baseline (1772.129 us; speedup 1.0000x reference)
//
#include <hip/hip_runtime.h>
#include <hip/hip_bf16.h>

#define S_LEN 2048
#define DMODEL 512
#define NH 8
#define DH 64
#define TOPK 32
#define CMAX 128

// ---------------------------------------------------------------------------
// GEMM: C[8192x512] = X[8192x512] @ W[512x512] + bias
// mode 0: write head-split layout [B,H,S,dh]; mode 1: plain row-major [M,512]
// 128x128 tile, BK=16, 256 threads, 8x8 microtile (fp32 vector ALU).
// ---------------------------------------------------------------------------
__global__ __launch_bounds__(256)
void gemm_proj(const float* __restrict__ X, const float* __restrict__ W,
               const float* __restrict__ bias, float* __restrict__ out, int mode)
{
    __shared__ float As[16][132];   // [k][m], transposed for outer-product reads
    __shared__ float Bs[16][132];   // [k][n]
    const int tid = threadIdx.x;
    const int tx = tid & 15;        // n direction
    const int ty = tid >> 4;        // m direction
    const int m0 = blockIdx.y * 128;
    const int n0 = blockIdx.x * 128;

    float acc[8][8];
#pragma unroll
    for (int i = 0; i < 8; ++i)
#pragma unroll
        for (int j = 0; j < 8; ++j) acc[i][j] = 0.f;

    for (int k0 = 0; k0 < 512; k0 += 16) {
#pragma unroll
        for (int u = 0; u < 2; ++u) {
            int id = tid + u * 256;                 // 0..511
            int r  = id >> 2;                       // 0..127
            int c4 = (id & 3) * 4;                  // 0,4,8,12
            float4 a = *(const float4*)(X + (size_t)(m0 + r) * 512 + k0 + c4);
            As[c4 + 0][r] = a.x; As[c4 + 1][r] = a.y;
            As[c4 + 2][r] = a.z; As[c4 + 3][r] = a.w;
            int rb = id >> 5;                       // 0..15
            int cb = (id & 31) * 4;                 // 0..124
            *(float4*)&Bs[rb][cb] = *(const float4*)(W + (size_t)(k0 + rb) * 512 + n0 + cb);
        }
        __syncthreads();
#pragma unroll
        for (int kk = 0; kk < 16; ++kk) {
            float a[8], b[8];
            *(float4*)&a[0] = *(const float4*)&As[kk][ty * 8];
            *(float4*)&a[4] = *(const float4*)&As[kk][ty * 8 + 4];
            *(float4*)&b[0] = *(const float4*)&Bs[kk][tx * 8];
            *(float4*)&b[4] = *(const float4*)&Bs[kk][tx * 8 + 4];
#pragma unroll
            for (int i = 0; i < 8; ++i)
#pragma unroll
                for (int j = 0; j < 8; ++j)
                    acc[i][j] = fmaf(a[i], b[j], acc[i][j]);
        }
        __syncthreads();
    }

    float bb[8];
    *(float4*)&bb[0] = *(const float4*)(bias + n0 + tx * 8);
    *(float4*)&bb[4] = *(const float4*)(bias + n0 + tx * 8 + 4);

    const int c = n0 + tx * 8;                      // multiple of 8; 8 cols stay in one head
#pragma unroll
    for (int i = 0; i < 8; ++i) {
        int r = m0 + ty * 8 + i;
        float4 w0 = make_float4(acc[i][0] + bb[0], acc[i][1] + bb[1],
                                acc[i][2] + bb[2], acc[i][3] + bb[3]);
        float4 w1 = make_float4(acc[i][4] + bb[4], acc[i][5] + bb[5],
                                acc[i][6] + bb[6], acc[i][7] + bb[7]);
        if (mode == 0) {
            int b_ = r >> 11, s = r & 2047, h = c >> 6, d = c & 63;
            float* p = out + (((size_t)(b_ * NH + h) * S_LEN) + s) * DH + d;
            *(float4*)p = w0; *(float4*)(p + 4) = w1;
        } else {
            float* p = out + (size_t)r * 512 + c;
            *(float4*)p = w0; *(float4*)(p + 4) = w1;
        }
    }
}

// ---------------------------------------------------------------------------
// Logits: per (b,h): L[2048x2048] = 0.125 * Qh[2048x64] @ Kh[2048x64]^T
// 128x128 tile, K-dim 64 in two 32-chunks, 8x8 microtile. Written fp32 into
// the w region of d_out (used as scratch; later overwritten by topk_attn).
// ---------------------------------------------------------------------------
__global__ __launch_bounds__(256)
void gemm_logits(const float* __restrict__ Qh, const float* __restrict__ Kh,
                 float* __restrict__ logits)
{
    __shared__ float As[32][132];   // [kdim][q]   (Q pre-scaled by 0.125)
    __shared__ float Bs[32][132];   // [kdim][key]
    const int tid = threadIdx.x;
    const int tx = tid & 15;        // key direction
    const int ty = tid >> 4;        // q direction
    const int bh = blockIdx.z;
    const float* Ab = Qh + (size_t)bh * S_LEN * DH;
    const float* Bb = Kh + (size_t)bh * S_LEN * DH;
    const int q0 = blockIdx.y * 128;
    const int k0 = blockIdx.x * 128;

    float acc[8][8];
#pragma unroll
    for (int i = 0; i < 8; ++i)
#pragma unroll
        for (int j = 0; j < 8; ++j) acc[i][j] = 0.f;

    for (int kh = 0; kh < 64; kh += 32) {
#pragma unroll
        for (int u = 0; u < 4; ++u) {
            int id = tid + u * 256;                 // 0..1023
            int r  = id >> 3;                       // 0..127
            int c4 = (id & 7) * 4;                  // 0..28
            float4 a = *(const float4*)(Ab + (size_t)(q0 + r) * DH + kh + c4);
            As[c4 + 0][r] = a.x * 0.125f; As[c4 + 1][r] = a.y * 0.125f;
            As[c4 + 2][r] = a.z * 0.125f; As[c4 + 3][r] = a.w * 0.125f;
            float4 b = *(const float4*)(Bb + (size_t)(k0 + r) * DH + kh + c4);
            Bs[c4 + 0][r] = b.x; Bs[c4 + 1][r] = b.y;
            Bs[c4 + 2][r] = b.z; Bs[c4 + 3][r] = b.w;
        }
        __syncthreads();
#pragma unroll
        for (int kk = 0; kk < 32; ++kk) {
            float a[8], b[8];
            *(float4*)&a[0] = *(const float4*)&As[kk][ty * 8];
            *(float4*)&a[4] = *(const float4*)&As[kk][ty * 8 + 4];
            *(float4*)&b[0] = *(const float4*)&Bs[kk][tx * 8];
            *(float4*)&b[4] = *(const float4*)&Bs[kk][tx * 8 + 4];
#pragma unroll
            for (int i = 0; i < 8; ++i)
#pragma unroll
                for (int j = 0; j < 8; ++j)
                    acc[i][j] = fmaf(a[i], b[j], acc[i][j]);
        }
        __syncthreads();
    }

    float* C = logits + (size_t)bh * S_LEN * S_LEN + (size_t)(q0 + ty * 8) * S_LEN + k0 + tx * 8;
#pragma unroll
    for (int i = 0; i < 8; ++i) {
        *(float4*)(C + (size_t)i * S_LEN)     = make_float4(acc[i][0], acc[i][1], acc[i][2], acc[i][3]);
        *(float4*)(C + (size_t)i * S_LEN + 4) = make_float4(acc[i][4], acc[i][5], acc[i][6], acc[i][7]);
    }
}

// ---------------------------------------------------------------------------
// Top-k + renorm + sparse attention.  One wave per query row (4 rows/block).
// Reads its fp32 logits row (in the w buffer), selects exact top-32 with
// jax-compatible index tie-break, writes the sparse renormalized w row back
// in place, and accumulates attn = sum w_i * V[idx_i] into the concat buffer.
// Note: renormalized weights = exp(l-m)/sum_top32 exp(l-m)  (full softmax Z cancels).
// ---------------------------------------------------------------------------
__device__ __forceinline__ unsigned sortable_u(float f) {
    unsigned u = __float_as_uint(f);
    unsigned msk = (unsigned)(((int)u) >> 31) | 0x80000000u;
    return u ^ msk;                 // monotone: a<b (float) <=> u(a)<u(b) (uint)
}

__global__ __launch_bounds__(256)
void topk_attn(float* __restrict__ wbuf, const float* __restrict__ Vh,
               float* __restrict__ att)
{
    __shared__ float wrow[4][2048];
    __shared__ float cand_v[4][CMAX];
    __shared__ int   cand_i[4][CMAX];
    __shared__ float win_e[4][TOPK];
    __shared__ int   win_i[4][TOPK];

    const int tid  = threadIdx.x;
    const int wv   = tid >> 6;
    const int lane = tid & 63;
    const unsigned long long lt = (1ull << lane) - 1ull;
    const int row = blockIdx.x * 4 + wv;        // (b*8+h)*2048 + s
    float* wr = wbuf + (size_t)row * 2048;

    // safety init (only matters in degenerate tie pathologies)
    if (lane < TOPK) { win_e[wv][lane] = 0.f; win_i[wv][lane] = 0; }

    float L[32];
#pragma unroll
    for (int t = 0; t < 8; ++t) {
        float4 x = *(const float4*)(wr + t * 256 + lane * 4);
        L[4 * t + 0] = x.x; L[4 * t + 1] = x.y; L[4 * t + 2] = x.z; L[4 * t + 3] = x.w;
    }

    float m = L[0];
#pragma unroll
    for (int t = 1; t < 32; ++t) m = fmaxf(m, L[t]);
#pragma unroll
    for (int off = 32; off > 0; off >>= 1) m = fmaxf(m, __shfl_xor(m, off, 64));

    auto wcount = [&](float T) -> int {
        int c = 0;
#pragma unroll
        for (int t = 0; t < 32; ++t) c += (L[t] >= T) ? 1 : 0;
#pragma unroll
        for (int off = 32; off > 0; off >>= 1) c += __shfl_xor(c, off, 64);
        return c;                    // wave-uniform
    };

    // find threshold Tlo with 32 <= count(l >= Tlo) <= CMAX
    float delta = 8.f;
    int clo = wcount(m - delta);
    int guard = 0;
    while (clo < TOPK && guard < 8) { delta *= 16.f; clo = wcount(m - delta); ++guard; }
    float Tlo = m - delta, Thi = m;
    guard = 0;
    while (clo > CMAX && guard < 24) {
        float mid = 0.5f * (Tlo + Thi);
        int cc = wcount(mid);
        if (cc >= TOPK) { Tlo = mid; clo = cc; } else { Thi = mid; }
        ++guard;
    }
    const int nc = min(clo, CMAX);

    // compact candidates (val, key-index) into LDS via ballot prefix
    int base = 0;
#pragma unroll
    for (int t = 0; t < 32; ++t) {
        bool p = (L[t] >= Tlo);
        unsigned long long mk = __ballot(p);
        if (p) {
            int pos = base + (int)__popcll(mk & lt);
            if (pos < CMAX) {
                cand_v[wv][pos] = L[t];
                cand_i[wv][pos] = (t >> 2) * 256 + lane * 4 + (t & 3);
            }
        }
        base += (int)__popcll(mk);
    }
    __syncthreads();

    // exact rank among candidates; ties -> lower index wins (jax top_k order)
    float mysum = 0.f;
    int wbase = 0;
#pragma unroll
    for (int it = 0; it < CMAX / 64; ++it) {
        int ci = it * 64 + lane;
        bool have = ci < nc;
        float v = have ? cand_v[wv][ci] : -3.0e38f;
        int  ki = have ? cand_i[wv][ci] : 0x7fffffff;
        unsigned uv = sortable_u(v);
        int rank = 0;
        for (int j = 0; j < nc; ++j) {
            unsigned uj = sortable_u(cand_v[wv][j]);
            int kj = cand_i[wv][j];
            rank += ((uj > uv) || (uj == uv && kj < ki)) ? 1 : 0;
        }
        bool win = have && (rank < TOPK);
        unsigned long long mk = __ballot(win);
        if (win) {
            int pos = wbase + (int)__popcll(mk & lt);
            float e = __expf(v - m);
            win_e[wv][pos] = e;
            win_i[wv][pos] = ki;
            mysum += e;
        }
        wbase += (int)__popcll(mk);
    }
#pragma unroll
    for (int off = 32; off > 0; off >>= 1) mysum += __shfl_xor(mysum, off, 64);
    const float rw = 1.f / mysum;
    __syncthreads();

    // build the sparse w row in LDS, then stream it out (fully overwrites scratch)
    const float4 z = make_float4(0.f, 0.f, 0.f, 0.f);
#pragma unroll
    for (int t = 0; t < 8; ++t) ((float4*)wrow[wv])[t * 64 + lane] = z;
    __syncthreads();
    if (lane < TOPK) wrow[wv][win_i[wv][lane] & 2047] = win_e[wv][lane] * rw;
    __syncthreads();
#pragma unroll
    for (int t = 0; t < 8; ++t)
        *(float4*)(wr + (size_t)(t * 64 + lane) * 4) = ((float4*)wrow[wv])[t * 64 + lane];

    // sparse attention: 32 weighted V rows; lane = head-dim index
    const int bh = row >> 11;
    const float* Vb = Vh + (size_t)bh * S_LEN * DH;
    float acc = 0.f;
#pragma unroll 4
    for (int j = 0; j < TOPK; ++j) {
        float wj = win_e[wv][j] * rw;
        int   kj = win_i[wv][j];
        acc = fmaf(wj, Vb[(size_t)kj * DH + lane], acc);
    }
    const int b_ = row >> 14;
    const int h  = (row >> 11) & 7;
    const int s  = row & 2047;
    att[((size_t)(b_ * S_LEN) + s) * DMODEL + h * DH + lane] = acc;
}

// ---------------------------------------------------------------------------
extern "C" void kernel_launch(void* const* d_in, const int* in_sizes, int n_in,
                              void* d_out, int out_size, void* d_ws, size_t ws_size,
                              hipStream_t stream) {
    const float* v  = (const float*)d_in[0];
    const float* k  = (const float*)d_in[1];
    const float* q  = (const float*)d_in[2];
    const float* Wq = (const float*)d_in[3];
    const float* bq = (const float*)d_in[4];
    const float* Wk = (const float*)d_in[5];
    const float* bk = (const float*)d_in[6];
    const float* Wv = (const float*)d_in[7];
    const float* bv = (const float*)d_in[8];
    const float* Wo = (const float*)d_in[9];
    const float* bo = (const float*)d_in[10];
    // top_k (d_in[11]) is the constant 32 == TOPK

    float* out  = (float*)d_out;                    // [4,2048,512]
    float* wout = out + (size_t)4 * S_LEN * DMODEL; // [4,8,2048,2048]; also logits scratch

    float* ws  = (float*)d_ws;                      // 4 x 16.8 MB = 67 MB
    float* Qh  = ws;                                // [B,H,S,dh]
    float* Kh  = ws + (size_t)4194304;
    float* Vh  = ws + (size_t)8388608;
    float* att = ws + (size_t)12582912;             // concat [B,S,D]

    dim3 gP(4, 64);   // 512/128 x 8192/128
    gemm_proj<<<gP, 256, 0, stream>>>(q, Wq, bq, Qh, 0);
    gemm_proj<<<gP, 256, 0, stream>>>(k, Wk, bk, Kh, 0);
    gemm_proj<<<gP, 256, 0, stream>>>(v, Wv, bv, Vh, 0);

    gemm_logits<<<dim3(16, 16, 32), 256, 0, stream>>>(Qh, Kh, wout);

    topk_attn<<<16384, 256, 0, stream>>>(wout, Vh, att);

    gemm_proj<<<gP, 256, 0, stream>>>(att, Wo, bo, out, 1);
}

// Round 5
// 1298.919 us; speedup vs baseline: 1.3643x; 1.3643x over previous
//
#include <hip/hip_runtime.h>
#include <hip/hip_bf16.h>
#include <stdint.h>

#define S_LEN 2048
#define DMODEL 512
#define NH 8
#define DH 64
#define TOPK 32
#define CMAX 128
#define LO_SCALE 4096.0f
#define INV_LO (1.0f/4096.0f)

typedef _Float16 f16;
typedef f16 half8 __attribute__((ext_vector_type(8)));
typedef f16 half4 __attribute__((ext_vector_type(4)));
typedef float floatx4 __attribute__((ext_vector_type(4)));
typedef float f32x4 __attribute__((ext_vector_type(4)));

#define AS1 __attribute__((address_space(1)))
#define AS3 __attribute__((address_space(3)))

__device__ __forceinline__ void gl_lds16(const void* g, void* l) {
    __builtin_amdgcn_global_load_lds((const AS1 void*)g, (AS3 void*)l, 16, 0, 0);
}

// ---------------------------------------------------------------------------
// R1-verbatim fp32 GEMM: C[8192x512] = X @ W + bias, head-split write.
// SELECTION-CRITICAL: sequential-K fp32 fma chain matches np/jax rounding —
// do not alter arithmetic (R1 passed with zero top-k flips).
// ---------------------------------------------------------------------------
__global__ __launch_bounds__(256)
void gemm_proj(const float* __restrict__ X, const float* __restrict__ W,
               const float* __restrict__ bias, float* __restrict__ out, int mode)
{
    __shared__ float As[16][132];   // [k][m]
    __shared__ float Bs[16][132];   // [k][n]
    const int tid = threadIdx.x;
    const int tx = tid & 15;        // n direction
    const int ty = tid >> 4;        // m direction
    const int m0 = blockIdx.y * 128;
    const int n0 = blockIdx.x * 128;

    float acc[8][8];
#pragma unroll
    for (int i = 0; i < 8; ++i)
#pragma unroll
        for (int j = 0; j < 8; ++j) acc[i][j] = 0.f;

    for (int k0 = 0; k0 < 512; k0 += 16) {
#pragma unroll
        for (int u = 0; u < 2; ++u) {
            int id = tid + u * 256;
            int r  = id >> 2;
            int c4 = (id & 3) * 4;
            float4 a = *(const float4*)(X + (size_t)(m0 + r) * 512 + k0 + c4);
            As[c4 + 0][r] = a.x; As[c4 + 1][r] = a.y;
            As[c4 + 2][r] = a.z; As[c4 + 3][r] = a.w;
            int rb = id >> 5;
            int cb = (id & 31) * 4;
            *(float4*)&Bs[rb][cb] = *(const float4*)(W + (size_t)(k0 + rb) * 512 + n0 + cb);
        }
        __syncthreads();
#pragma unroll
        for (int kk = 0; kk < 16; ++kk) {
            float a[8], b[8];
            *(float4*)&a[0] = *(const float4*)&As[kk][ty * 8];
            *(float4*)&a[4] = *(const float4*)&As[kk][ty * 8 + 4];
            *(float4*)&b[0] = *(const float4*)&Bs[kk][tx * 8];
            *(float4*)&b[4] = *(const float4*)&Bs[kk][tx * 8 + 4];
#pragma unroll
            for (int i = 0; i < 8; ++i)
#pragma unroll
                for (int j = 0; j < 8; ++j)
                    acc[i][j] = fmaf(a[i], b[j], acc[i][j]);
        }
        __syncthreads();
    }

    float bb[8];
    *(float4*)&bb[0] = *(const float4*)(bias + n0 + tx * 8);
    *(float4*)&bb[4] = *(const float4*)(bias + n0 + tx * 8 + 4);

    const int c = n0 + tx * 8;
#pragma unroll
    for (int i = 0; i < 8; ++i) {
        int r = m0 + ty * 8 + i;
        float4 w0 = make_float4(acc[i][0] + bb[0], acc[i][1] + bb[1],
                                acc[i][2] + bb[2], acc[i][3] + bb[3]);
        float4 w1 = make_float4(acc[i][4] + bb[4], acc[i][5] + bb[5],
                                acc[i][6] + bb[6], acc[i][7] + bb[7]);
        if (mode == 0) {
            int b_ = r >> 11, s = r & 2047, h = c >> 6, d = c & 63;
            float* p = out + (((size_t)(b_ * NH + h) * S_LEN) + s) * DH + d;
            *(float4*)p = w0; *(float4*)(p + 4) = w1;
        } else {
            float* p = out + (size_t)r * 512 + c;
            *(float4*)p = w0; *(float4*)(p + 4) = w1;
        }
    }
}

// ---------------------------------------------------------------------------
// R1-verbatim fp32 logits: per (b,h): L = 0.125*Qh @ Kh^T.  SELECTION-
// CRITICAL (see gemm_proj note).
// ---------------------------------------------------------------------------
__global__ __launch_bounds__(256)
void gemm_logits(const float* __restrict__ Qh, const float* __restrict__ Kh,
                 float* __restrict__ logits)
{
    __shared__ float As[32][132];
    __shared__ float Bs[32][132];
    const int tid = threadIdx.x;
    const int tx = tid & 15;
    const int ty = tid >> 4;
    const int bh = blockIdx.z;
    const float* Ab = Qh + (size_t)bh * S_LEN * DH;
    const float* Bb = Kh + (size_t)bh * S_LEN * DH;
    const int q0 = blockIdx.y * 128;
    const int k0 = blockIdx.x * 128;

    float acc[8][8];
#pragma unroll
    for (int i = 0; i < 8; ++i)
#pragma unroll
        for (int j = 0; j < 8; ++j) acc[i][j] = 0.f;

    for (int kh = 0; kh < 64; kh += 32) {
#pragma unroll
        for (int u = 0; u < 4; ++u) {
            int id = tid + u * 256;
            int r  = id >> 3;
            int c4 = (id & 7) * 4;
            float4 a = *(const float4*)(Ab + (size_t)(q0 + r) * DH + kh + c4);
            As[c4 + 0][r] = a.x * 0.125f; As[c4 + 1][r] = a.y * 0.125f;
            As[c4 + 2][r] = a.z * 0.125f; As[c4 + 3][r] = a.w * 0.125f;
            float4 b = *(const float4*)(Bb + (size_t)(k0 + r) * DH + kh + c4);
            Bs[c4 + 0][r] = b.x; Bs[c4 + 1][r] = b.y;
            Bs[c4 + 2][r] = b.z; Bs[c4 + 3][r] = b.w;
        }
        __syncthreads();
#pragma unroll
        for (int kk = 0; kk < 32; ++kk) {
            float a[8], b[8];
            *(float4*)&a[0] = *(const float4*)&As[kk][ty * 8];
            *(float4*)&a[4] = *(const float4*)&As[kk][ty * 8 + 4];
            *(float4*)&b[0] = *(const float4*)&Bs[kk][tx * 8];
            *(float4*)&b[4] = *(const float4*)&Bs[kk][tx * 8 + 4];
#pragma unroll
            for (int i = 0; i < 8; ++i)
#pragma unroll
                for (int j = 0; j < 8; ++j)
                    acc[i][j] = fmaf(a[i], b[j], acc[i][j]);
        }
        __syncthreads();
    }

    float* C = logits + (size_t)bh * S_LEN * S_LEN + (size_t)(q0 + ty * 8) * S_LEN + k0 + tx * 8;
#pragma unroll
    for (int i = 0; i < 8; ++i) {
        *(float4*)(C + (size_t)i * S_LEN)     = make_float4(acc[i][0], acc[i][1], acc[i][2], acc[i][3]);
        *(float4*)(C + (size_t)i * S_LEN + 4) = make_float4(acc[i][4], acc[i][5], acc[i][6], acc[i][7]);
    }
}

// ---------------------------------------------------------------------------
// Weight transpose + fp16 hi/lo split for Wv (z=0) and Wo (z=1) only.
// ---------------------------------------------------------------------------
__global__ __launch_bounds__(256)
void wsplit2(const float* __restrict__ W0, const float* __restrict__ W1,
             f16* __restrict__ planes)
{
    __shared__ float tile[32][33];
    const float* W = blockIdx.z ? W1 : W0;
    f16* Th = planes + (size_t)blockIdx.z * 524288;
    f16* Tl = Th + 262144;
    const int bx = blockIdx.x * 32;
    const int by = blockIdx.y * 32;
    const int lx = threadIdx.x & 31, ly = threadIdx.x >> 5;
#pragma unroll
    for (int r = ly; r < 32; r += 8)
        tile[r][lx] = W[(size_t)(by + r) * 512 + bx + lx];
    __syncthreads();
#pragma unroll
    for (int r = ly; r < 32; r += 8) {
        float x = tile[lx][r];              // = W[by+lx][bx+r]
        f16 h = (f16)x;
        f16 l = (f16)((x - (float)h) * LO_SCALE);
        Th[(size_t)(bx + r) * 512 + by + lx] = h;
        Tl[(size_t)(bx + r) * 512 + by + lx] = l;
    }
}

// ---------------------------------------------------------------------------
// Split-fp16 MFMA GEMM, A fp32 (in-kernel split): used ONLY for the V
// projection (selection-irrelevant; error ~3e-7 on vh -> ~1e-6 on out).
// mode 1 = fp32 head-split write.
// ---------------------------------------------------------------------------
__global__ __launch_bounds__(256)
void gemm_x32(const float* __restrict__ X,
              const f16* __restrict__ Bh_, const f16* __restrict__ Bl_,
              const float* __restrict__ bias, float* __restrict__ outF, int mode)
{
    __shared__ f16 sm[16384];
    f16* As_h = sm;       f16* As_l = sm + 4096;
    f16* Bs_h = sm + 8192; f16* Bs_l = sm + 12288;
    const int tid  = threadIdx.x;
    const int lane = tid & 63, wv = tid >> 6;
    const int wm = wv & 1, wn = wv >> 1;
    const int quad = lane >> 4, l15 = lane & 15;
    const int m0 = blockIdx.y * 128, n0 = blockIdx.x * 128;

    floatx4 acc_h[4][4], acc_c[4][4];
    const floatx4 z4 = {0.f, 0.f, 0.f, 0.f};
#pragma unroll
    for (int i = 0; i < 4; ++i)
#pragma unroll
        for (int j = 0; j < 4; ++j) { acc_h[i][j] = z4; acc_c[i][j] = z4; }

    for (int k0 = 0; k0 < 512; k0 += 32) {
        __syncthreads();
#pragma unroll
        for (int c = 0; c < 4; ++c) {
            int r   = c * 32 + (tid >> 3);
            int col = (tid & 7) * 4;
            float4 x = *(const float4*)(X + (size_t)(m0 + r) * 512 + k0 + col);
            f16 h0 = (f16)x.x, h1 = (f16)x.y, h2 = (f16)x.z, h3 = (f16)x.w;
            half4 hv = {h0, h1, h2, h3};
            half4 lv = {(f16)((x.x - (float)h0) * LO_SCALE),
                        (f16)((x.y - (float)h1) * LO_SCALE),
                        (f16)((x.z - (float)h2) * LO_SCALE),
                        (f16)((x.w - (float)h3) * LO_SCALE)};
            *(half4*)&As_h[r * 32 + col] = hv;
            *(half4*)&As_l[r * 32 + col] = lv;
        }
#pragma unroll
        for (int c = 0; c < 2; ++c) {
            int r    = c * 64 + (wv << 4) + (lane >> 2);
            int ch   = (lane & 3) * 8;
            int lidx = (c * 64 + (wv << 4)) * 32 + lane * 8;
            gl_lds16(Bh_ + (size_t)(n0 + r) * 512 + k0 + ch, &Bs_h[lidx]);
            gl_lds16(Bl_ + (size_t)(n0 + r) * 512 + k0 + ch, &Bs_l[lidx]);
        }
        asm volatile("s_waitcnt vmcnt(0)" ::: "memory");
        __syncthreads();

        half8 bh8[4], bl8[4];
#pragma unroll
        for (int j = 0; j < 4; ++j) {
            int n = wn * 64 + j * 16 + l15;
            bh8[j] = *(const half8*)&Bs_h[n * 32 + quad * 8];
            bl8[j] = *(const half8*)&Bs_l[n * 32 + quad * 8];
        }
#pragma unroll
        for (int i = 0; i < 4; ++i) {
            int m = wm * 64 + i * 16 + l15;
            half8 ah = *(const half8*)&As_h[m * 32 + quad * 8];
            half8 al = *(const half8*)&As_l[m * 32 + quad * 8];
#pragma unroll
            for (int j = 0; j < 4; ++j) {
                acc_h[i][j] = __builtin_amdgcn_mfma_f32_16x16x32_f16(ah, bh8[j], acc_h[i][j], 0, 0, 0);
                acc_c[i][j] = __builtin_amdgcn_mfma_f32_16x16x32_f16(ah, bl8[j], acc_c[i][j], 0, 0, 0);
                acc_c[i][j] = __builtin_amdgcn_mfma_f32_16x16x32_f16(al, bh8[j], acc_c[i][j], 0, 0, 0);
            }
        }
    }

#pragma unroll
    for (int j = 0; j < 4; ++j) {
        int col = n0 + wn * 64 + j * 16 + l15;
        float bv = bias[col];
#pragma unroll
        for (int i = 0; i < 4; ++i) {
            int rbase = m0 + wm * 64 + i * 16 + quad * 4;
#pragma unroll
            for (int rg = 0; rg < 4; ++rg) {
                float r = acc_h[i][j][rg] + acc_c[i][j][rg] * INV_LO + bv;
                int row = rbase + rg;
                if (mode == 2) {
                    outF[(size_t)row * 512 + col] = r;
                } else {
                    int b_ = row >> 11, s = row & 2047, h = col >> 6, d = col & 63;
                    outF[(((size_t)(b_ * NH + h)) * S_LEN + s) * DH + d] = r;
                }
            }
        }
    }
}

// ---------------------------------------------------------------------------
// Split-fp16 MFMA GEMM, both operands pre-split planes [row][k].
// mode 2: out-proj (K=512, C = A@B^T + bias, fp32 [8192][512]).
// Selection-irrelevant path.
// ---------------------------------------------------------------------------
__global__ __launch_bounds__(256)
void gemm_x16(const f16* __restrict__ Ah_, const f16* __restrict__ Al_,
              const f16* __restrict__ Bh_, const f16* __restrict__ Bl_,
              const float* __restrict__ bias, float* __restrict__ outF,
              int Ksz, int ldc, int mode)
{
    __shared__ f16 sm[16384];
    f16* As_h = sm;        f16* As_l = sm + 4096;
    f16* Bs_h = sm + 8192; f16* Bs_l = sm + 12288;
    const int tid  = threadIdx.x;
    const int lane = tid & 63, wv = tid >> 6;
    const int wm = wv & 1, wn = wv >> 1;
    const int quad = lane >> 4, l15 = lane & 15;
    const int m0 = blockIdx.y * 128, n0 = blockIdx.x * 128;

    floatx4 acc_h[4][4], acc_c[4][4];
    const floatx4 z4 = {0.f, 0.f, 0.f, 0.f};
#pragma unroll
    for (int i = 0; i < 4; ++i)
#pragma unroll
        for (int j = 0; j < 4; ++j) { acc_h[i][j] = z4; acc_c[i][j] = z4; }

    for (int k0 = 0; k0 < Ksz; k0 += 32) {
        __syncthreads();
#pragma unroll
        for (int c = 0; c < 2; ++c) {
            int r    = c * 64 + (wv << 4) + (lane >> 2);
            int ch   = (lane & 3) * 8;
            int lidx = (c * 64 + (wv << 4)) * 32 + lane * 8;
            gl_lds16(Ah_ + (size_t)(m0 + r) * Ksz + k0 + ch, &As_h[lidx]);
            gl_lds16(Al_ + (size_t)(m0 + r) * Ksz + k0 + ch, &As_l[lidx]);
            gl_lds16(Bh_ + (size_t)(n0 + r) * Ksz + k0 + ch, &Bs_h[lidx]);
            gl_lds16(Bl_ + (size_t)(n0 + r) * Ksz + k0 + ch, &Bs_l[lidx]);
        }
        asm volatile("s_waitcnt vmcnt(0)" ::: "memory");
        __syncthreads();

        half8 bh8[4], bl8[4];
#pragma unroll
        for (int j = 0; j < 4; ++j) {
            int n = wn * 64 + j * 16 + l15;
            bh8[j] = *(const half8*)&Bs_h[n * 32 + quad * 8];
            bl8[j] = *(const half8*)&Bs_l[n * 32 + quad * 8];
        }
#pragma unroll
        for (int i = 0; i < 4; ++i) {
            int m = wm * 64 + i * 16 + l15;
            half8 ah = *(const half8*)&As_h[m * 32 + quad * 8];
            half8 al = *(const half8*)&As_l[m * 32 + quad * 8];
#pragma unroll
            for (int j = 0; j < 4; ++j) {
                acc_h[i][j] = __builtin_amdgcn_mfma_f32_16x16x32_f16(ah, bh8[j], acc_h[i][j], 0, 0, 0);
                acc_c[i][j] = __builtin_amdgcn_mfma_f32_16x16x32_f16(ah, bl8[j], acc_c[i][j], 0, 0, 0);
                acc_c[i][j] = __builtin_amdgcn_mfma_f32_16x16x32_f16(al, bh8[j], acc_c[i][j], 0, 0, 0);
            }
        }
    }

#pragma unroll
    for (int j = 0; j < 4; ++j) {
        int col = n0 + wn * 64 + j * 16 + l15;
        float bv = (mode == 2) ? bias[col] : 0.f;
#pragma unroll
        for (int i = 0; i < 4; ++i) {
            int rbase = m0 + wm * 64 + i * 16 + quad * 4;
#pragma unroll
            for (int rg = 0; rg < 4; ++rg) {
                float r = acc_h[i][j][rg] + acc_c[i][j][rg] * INV_LO;
                int row = rbase + rg;
                outF[(size_t)row * ldc + col] = r + bv;
            }
        }
    }
}

// ---------------------------------------------------------------------------
// Top-k + renorm + sparse attention.  One wave per query row (4 rows/block).
// Semantically identical selection to the R1-passing kernel (exact rank with
// (value desc, index asc) tie-break via packed u64 keys); faster: ballot
// counts, bisect to <=64 candidates, NT row stores.  att written as f16
// hi/lo planes for the split out-projection.
// ---------------------------------------------------------------------------
__device__ __forceinline__ unsigned sortable_u(float f) {
    unsigned u = __float_as_uint(f);
    return u ^ ((unsigned)(((int)u) >> 31) | 0x80000000u);
}

__global__ __launch_bounds__(256)
void topk_attn(float* __restrict__ wbuf, const float* __restrict__ Vh,
               f16* __restrict__ attH, f16* __restrict__ attL)
{
    __shared__ float    wrow[4][2048];
    __shared__ uint64_t cand[4][CMAX];
    __shared__ float    win_w[4][TOPK];
    __shared__ int      win_i[4][TOPK];

    const int tid  = threadIdx.x;
    const int wv   = tid >> 6;
    const int lane = tid & 63;
    const unsigned long long lt = (1ull << lane) - 1ull;
    const int row = blockIdx.x * 4 + wv;        // (b*8+h)*2048 + s
    float* wr = wbuf + (size_t)row * 2048;

    if (lane < TOPK) { win_w[wv][lane] = 0.f; win_i[wv][lane] = 0; }

    float L[32];
#pragma unroll
    for (int t = 0; t < 8; ++t) {
        f32x4 x = *(const f32x4*)(wr + t * 256 + lane * 4);
        L[4 * t + 0] = x.x; L[4 * t + 1] = x.y; L[4 * t + 2] = x.z; L[4 * t + 3] = x.w;
    }

    float m = L[0];
#pragma unroll
    for (int t = 1; t < 32; ++t) m = fmaxf(m, L[t]);
#pragma unroll
    for (int off = 32; off > 0; off >>= 1) m = fmaxf(m, __shfl_xor(m, off, 64));

    auto wcount = [&](float T) -> int {
        int c = 0;
#pragma unroll
        for (int t = 0; t < 32; ++t) c += (int)__popcll(__ballot(L[t] >= T));
        return c;                    // wave-uniform
    };

    // threshold Tlo with 32 <= count(l >= Tlo), narrowed until count <= 64
    float delta = 2.f;
    int clo = wcount(m - delta);
    int guard = 0;
    while (clo < TOPK && guard < 8) { delta *= 16.f; clo = wcount(m - delta); ++guard; }
    float Tlo = m - delta, Thi = m;
    guard = 0;
    while (clo > 64 && guard < 40) {
        float mid = 0.5f * (Tlo + Thi);
        int cc = wcount(mid);
        if (cc >= TOPK) { Tlo = mid; clo = cc; } else { Thi = mid; }
        ++guard;
    }
    const int nc = min(clo, CMAX);

    // compact candidates as packed sortable keys (value desc, index asc)
    int base = 0;
#pragma unroll
    for (int t = 0; t < 32; ++t) {
        bool p = (L[t] >= Tlo);
        unsigned long long mk = __ballot(p);
        if (p) {
            int pos = base + (int)__popcll(mk & lt);
            if (pos < CMAX) {
                int idx = (t >> 2) * 256 + (lane << 2) + (t & 3);
                cand[wv][pos] = ((uint64_t)sortable_u(L[t]) << 32) | (uint32_t)(~(uint32_t)idx);
            }
        }
        base += (int)__popcll(mk);
    }
    __syncthreads();

    // exact rank: winners = rank < 32 (u64 compare handles tie-break)
    float mysum = 0.f;
    int wbase = 0;
    const int passes = (nc + 63) >> 6;
    for (int it = 0; it < passes; ++it) {
        int ci = (it << 6) + lane;
        bool have = ci < nc;
        uint64_t mykey = have ? cand[wv][ci] : 0ull;
        int rank = 0;
#pragma unroll 8
        for (int j = 0; j < nc; ++j)
            rank += (cand[wv][j] > mykey) ? 1 : 0;
        bool win = have && (rank < TOPK);
        unsigned long long mk = __ballot(win);
        if (win) {
            int pos = wbase + (int)__popcll(mk & lt);
            unsigned uv = (unsigned)(mykey >> 32);
            unsigned fu = (uv & 0x80000000u) ? (uv ^ 0x80000000u) : ~uv;
            float v = __uint_as_float(fu);
            int idx = (int)(~(uint32_t)mykey);
            float e = __expf(v - m);
            win_w[wv][pos] = e;
            win_i[wv][pos] = idx;
            mysum += e;
        }
        wbase += (int)__popcll(mk);
    }
#pragma unroll
    for (int off = 32; off > 0; off >>= 1) mysum += __shfl_xor(mysum, off, 64);
    const float rw = 1.f / mysum;
    __syncthreads();

    // build sparse w row in LDS, stream out with NT stores
    const f32x4 z = {0.f, 0.f, 0.f, 0.f};
#pragma unroll
    for (int t = 0; t < 8; ++t) ((f32x4*)wrow[wv])[t * 64 + lane] = z;
    __syncthreads();
    if (lane < TOPK) wrow[wv][win_i[wv][lane] & 2047] = win_w[wv][lane] * rw;
    __syncthreads();
#pragma unroll
    for (int t = 0; t < 8; ++t)
        __builtin_nontemporal_store(((f32x4*)wrow[wv])[t * 64 + lane],
                                    (f32x4*)(wr + (size_t)(t * 64 + lane) * 4));

    // sparse attention: 32 weighted V rows; lane = head-dim index
    const int bh = row >> 11;
    const float* Vb = Vh + (size_t)bh * S_LEN * DH;
    float acc = 0.f;
#pragma unroll
    for (int j = 0; j < TOPK; ++j) {
        float wj = win_w[wv][j] * rw;
        int   kj = win_i[wv][j];
        acc = fmaf(wj, Vb[(size_t)kj * DH + lane], acc);
    }
    const int b_ = row >> 14;
    const int h  = (row >> 11) & 7;
    const int s  = row & 2047;
    size_t oidx = (((size_t)b_ * S_LEN) + s) * 512 + h * DH + lane;
    f16 hh = (f16)acc;
    attH[oidx] = hh;
    attL[oidx] = (f16)((acc - (float)hh) * LO_SCALE);
}

// ---------------------------------------------------------------------------
extern "C" void kernel_launch(void* const* d_in, const int* in_sizes, int n_in,
                              void* d_out, int out_size, void* d_ws, size_t ws_size,
                              hipStream_t stream) {
    const float* v  = (const float*)d_in[0];
    const float* k  = (const float*)d_in[1];
    const float* q  = (const float*)d_in[2];
    const float* Wq = (const float*)d_in[3];
    const float* bq = (const float*)d_in[4];
    const float* Wk = (const float*)d_in[5];
    const float* bk = (const float*)d_in[6];
    const float* Wv = (const float*)d_in[7];
    const float* bv = (const float*)d_in[8];
    const float* Wo = (const float*)d_in[9];
    const float* bo = (const float*)d_in[10];

    float* out  = (float*)d_out;                    // [4,2048,512]
    float* wout = out + (size_t)4 * S_LEN * 512;    // [4,8,2048,2048] (logits scratch, then w)

    char* ws = (char*)d_ws;
    float* Vh   = (float*)ws;                       // fp32 [B,H,S,dh], 16 MB
    float* Qh32 = (float*)(ws + 16777216);          // fp32 [B,H,S,dh], 16 MB
    float* Kh32 = (float*)(ws + 33554432);          // fp32 [B,H,S,dh], 16 MB
    f16* WT  = (f16*)(ws + 50331648);               // 4 planes of 512x512, 2 MB
    f16 *WvH = WT,           *WvL = WT + 262144;
    f16 *WoH = WT + 524288,  *WoL = WT + 786432;
    // att planes alias Qh32 (dead after gemm_logits): 8 MB + 8 MB
    f16* attH = (f16*)(ws + 16777216);
    f16* attL = (f16*)(ws + 25165824);

    wsplit2<<<dim3(16, 16, 2), 256, 0, stream>>>(Wv, Wo, WT);

    dim3 gP(4, 64);
    gemm_proj<<<gP, 256, 0, stream>>>(q, Wq, bq, Qh32, 0);   // R1-exact (selection)
    gemm_proj<<<gP, 256, 0, stream>>>(k, Wk, bk, Kh32, 0);   // R1-exact (selection)
    gemm_x32<<<gP, 256, 0, stream>>>(v, WvH, WvL, bv, Vh, 1);

    gemm_logits<<<dim3(16, 16, 32), 256, 0, stream>>>(Qh32, Kh32, wout);  // R1-exact

    topk_attn<<<16384, 256, 0, stream>>>(wout, Vh, attH, attL);

    gemm_x16<<<dim3(4, 64, 1), 256, 0, stream>>>(attH, attL, WoH, WoL, bo, out, 512, 512, 2);
}

// Round 7
// 1121.422 us; speedup vs baseline: 1.5803x; 1.1583x over previous
//
#include <hip/hip_runtime.h>
#include <hip/hip_bf16.h>
#include <stdint.h>

#define S_LEN 2048
#define DMODEL 512
#define NH 8
#define DH 64
#define TOPK 32
#define CMAX 128
#define LO_SCALE 4096.0f
#define INV_LO (1.0f/4096.0f)

typedef _Float16 f16;
typedef f16 half8 __attribute__((ext_vector_type(8)));
typedef f16 half4 __attribute__((ext_vector_type(4)));
typedef float floatx4 __attribute__((ext_vector_type(4)));
typedef float f32x4 __attribute__((ext_vector_type(4)));

#define AS1 __attribute__((address_space(1)))
#define AS3 __attribute__((address_space(3)))

__device__ __forceinline__ void gl_lds16(const void* g, void* l) {
    __builtin_amdgcn_global_load_lds((const AS1 void*)g, (AS3 void*)l, 16, 0, 0);
}
__device__ __forceinline__ void lds_fence() {
    asm volatile("s_waitcnt lgkmcnt(0)" ::: "memory");
}

// ---------------------------------------------------------------------------
// Merged Q+K projection (blockIdx.z selects), fp32 vector GEMM.
// SELECTION-CRITICAL: per-accumulator fma order is k=0..511 ascending with
// identical inputs -> BIT-IDENTICAL to the R5-passing gemm_proj.  Structural
// changes only: BK=32 (fewer barriers), register prefetch of next chunk
// (hides global latency behind compute), one dispatch for Q and K.
// ---------------------------------------------------------------------------
__global__ __launch_bounds__(256)
void qkproj(const float* __restrict__ Xq, const float* __restrict__ Xk,
            const float* __restrict__ Wq_, const float* __restrict__ Wk_,
            const float* __restrict__ bq_, const float* __restrict__ bk_,
            float* __restrict__ outQ, float* __restrict__ outK)
{
    __shared__ float As[32][132];   // [k][m]
    __shared__ float Bs[32][132];   // [k][n]
    const float* X    = blockIdx.z ? Xk  : Xq;
    const float* W    = blockIdx.z ? Wk_ : Wq_;
    const float* bias = blockIdx.z ? bk_ : bq_;
    float* out        = blockIdx.z ? outK : outQ;
    const int tid = threadIdx.x;
    const int tx = tid & 15;        // n direction
    const int ty = tid >> 4;        // m direction
    const int m0 = blockIdx.y * 128;
    const int n0 = blockIdx.x * 128;

    float acc[8][8];
#pragma unroll
    for (int i = 0; i < 8; ++i)
#pragma unroll
        for (int j = 0; j < 8; ++j) acc[i][j] = 0.f;

    f32x4 pa[4], pb[4];
#pragma unroll
    for (int u = 0; u < 4; ++u) {
        int id = tid + u * 256;
        pa[u] = *(const f32x4*)(X + (size_t)(m0 + (id >> 3)) * 512 + (id & 7) * 4);
        pb[u] = *(const f32x4*)(W + (size_t)(id >> 5) * 512 + n0 + (id & 31) * 4);
    }

    for (int k0 = 0; k0 < 512; k0 += 32) {
#pragma unroll
        for (int u = 0; u < 4; ++u) {
            int id = tid + u * 256;
            int r = id >> 3, c4 = (id & 7) * 4;
            As[c4 + 0][r] = pa[u].x; As[c4 + 1][r] = pa[u].y;
            As[c4 + 2][r] = pa[u].z; As[c4 + 3][r] = pa[u].w;
            int rb = id >> 5, cb = (id & 31) * 4;
            *(f32x4*)&Bs[rb][cb] = pb[u];
        }
        __syncthreads();
        if (k0 < 480) {
            int kn = k0 + 32;
#pragma unroll
            for (int u = 0; u < 4; ++u) {
                int id = tid + u * 256;
                pa[u] = *(const f32x4*)(X + (size_t)(m0 + (id >> 3)) * 512 + kn + (id & 7) * 4);
                pb[u] = *(const f32x4*)(W + (size_t)(kn + (id >> 5)) * 512 + n0 + (id & 31) * 4);
            }
        }
#pragma unroll
        for (int kk = 0; kk < 32; ++kk) {
            float a[8], b[8];
            *(f32x4*)&a[0] = *(const f32x4*)&As[kk][ty * 8];
            *(f32x4*)&a[4] = *(const f32x4*)&As[kk][ty * 8 + 4];
            *(f32x4*)&b[0] = *(const f32x4*)&Bs[kk][tx * 8];
            *(f32x4*)&b[4] = *(const f32x4*)&Bs[kk][tx * 8 + 4];
#pragma unroll
            for (int i = 0; i < 8; ++i)
#pragma unroll
                for (int j = 0; j < 8; ++j)
                    acc[i][j] = fmaf(a[i], b[j], acc[i][j]);
        }
        __syncthreads();
    }

    float bb[8];
    *(f32x4*)&bb[0] = *(const f32x4*)(bias + n0 + tx * 8);
    *(f32x4*)&bb[4] = *(const f32x4*)(bias + n0 + tx * 8 + 4);

    const int c = n0 + tx * 8;
#pragma unroll
    for (int i = 0; i < 8; ++i) {
        int r = m0 + ty * 8 + i;
        f32x4 w0 = {acc[i][0] + bb[0], acc[i][1] + bb[1], acc[i][2] + bb[2], acc[i][3] + bb[3]};
        f32x4 w1 = {acc[i][4] + bb[4], acc[i][5] + bb[5], acc[i][6] + bb[6], acc[i][7] + bb[7]};
        int b_ = r >> 11, s = r & 2047, h = c >> 6, d = c & 63;
        float* p = out + (((size_t)(b_ * NH + h) * S_LEN) + s) * DH + d;
        *(f32x4*)p = w0; *(f32x4*)(p + 4) = w1;
    }
}

// ---------------------------------------------------------------------------
// fp32 logits: per (b,h): L = 0.125*Qh @ Kh^T.  SELECTION-CRITICAL: fma
// order (kh chunk asc, kk asc) and 0.125 prescale-at-stage are IDENTICAL to
// the R5-passing kernel -> bit-identical logits.  Structural: register
// prefetch of chunk 1 during chunk 0 compute; NT stores (read-once scratch)
// via f32x4 ext-vector (HIP float4 is rejected by the NT builtin).
// ---------------------------------------------------------------------------
__global__ __launch_bounds__(256)
void gemm_logits(const float* __restrict__ Qh, const float* __restrict__ Kh,
                 float* __restrict__ logits)
{
    __shared__ float As[32][132];
    __shared__ float Bs[32][132];
    const int tid = threadIdx.x;
    const int tx = tid & 15;
    const int ty = tid >> 4;
    const int bh = blockIdx.z;
    const float* Ab = Qh + (size_t)bh * S_LEN * DH;
    const float* Bb = Kh + (size_t)bh * S_LEN * DH;
    const int q0 = blockIdx.y * 128;
    const int k0 = blockIdx.x * 128;

    float acc[8][8];
#pragma unroll
    for (int i = 0; i < 8; ++i)
#pragma unroll
        for (int j = 0; j < 8; ++j) acc[i][j] = 0.f;

    f32x4 qa[4], kb[4];
#pragma unroll
    for (int u = 0; u < 4; ++u) {
        int id = tid + u * 256;
        int r = id >> 3, c4 = (id & 7) * 4;
        qa[u] = *(const f32x4*)(Ab + (size_t)(q0 + r) * DH + c4);
        kb[u] = *(const f32x4*)(Bb + (size_t)(k0 + r) * DH + c4);
    }

    for (int ch = 0; ch < 2; ++ch) {
#pragma unroll
        for (int u = 0; u < 4; ++u) {
            int id = tid + u * 256;
            int r = id >> 3, c4 = (id & 7) * 4;
            As[c4 + 0][r] = qa[u].x * 0.125f; As[c4 + 1][r] = qa[u].y * 0.125f;
            As[c4 + 2][r] = qa[u].z * 0.125f; As[c4 + 3][r] = qa[u].w * 0.125f;
            Bs[c4 + 0][r] = kb[u].x; Bs[c4 + 1][r] = kb[u].y;
            Bs[c4 + 2][r] = kb[u].z; Bs[c4 + 3][r] = kb[u].w;
        }
        __syncthreads();
        if (ch == 0) {
#pragma unroll
            for (int u = 0; u < 4; ++u) {
                int id = tid + u * 256;
                int r = id >> 3, c4 = (id & 7) * 4;
                qa[u] = *(const f32x4*)(Ab + (size_t)(q0 + r) * DH + 32 + c4);
                kb[u] = *(const f32x4*)(Bb + (size_t)(k0 + r) * DH + 32 + c4);
            }
        }
#pragma unroll
        for (int kk = 0; kk < 32; ++kk) {
            float a[8], b[8];
            *(f32x4*)&a[0] = *(const f32x4*)&As[kk][ty * 8];
            *(f32x4*)&a[4] = *(const f32x4*)&As[kk][ty * 8 + 4];
            *(f32x4*)&b[0] = *(const f32x4*)&Bs[kk][tx * 8];
            *(f32x4*)&b[4] = *(const f32x4*)&Bs[kk][tx * 8 + 4];
#pragma unroll
            for (int i = 0; i < 8; ++i)
#pragma unroll
                for (int j = 0; j < 8; ++j)
                    acc[i][j] = fmaf(a[i], b[j], acc[i][j]);
        }
        __syncthreads();
    }

    float* C = logits + (size_t)bh * S_LEN * S_LEN + (size_t)(q0 + ty * 8) * S_LEN + k0 + tx * 8;
#pragma unroll
    for (int i = 0; i < 8; ++i) {
        f32x4 v0 = {acc[i][0], acc[i][1], acc[i][2], acc[i][3]};
        f32x4 v1 = {acc[i][4], acc[i][5], acc[i][6], acc[i][7]};
        __builtin_nontemporal_store(v0, (f32x4*)(C + (size_t)i * S_LEN));
        __builtin_nontemporal_store(v1, (f32x4*)(C + (size_t)i * S_LEN + 4));
    }
}

// ---------------------------------------------------------------------------
// Weight transpose + fp16 hi/lo split for Wv (z=0) and Wo (z=1) only.
// ---------------------------------------------------------------------------
__global__ __launch_bounds__(256)
void wsplit2(const float* __restrict__ W0, const float* __restrict__ W1,
             f16* __restrict__ planes)
{
    __shared__ float tile[32][33];
    const float* W = blockIdx.z ? W1 : W0;
    f16* Th = planes + (size_t)blockIdx.z * 524288;
    f16* Tl = Th + 262144;
    const int bx = blockIdx.x * 32;
    const int by = blockIdx.y * 32;
    const int lx = threadIdx.x & 31, ly = threadIdx.x >> 5;
#pragma unroll
    for (int r = ly; r < 32; r += 8)
        tile[r][lx] = W[(size_t)(by + r) * 512 + bx + lx];
    __syncthreads();
#pragma unroll
    for (int r = ly; r < 32; r += 8) {
        float x = tile[lx][r];              // = W[by+lx][bx+r]
        f16 h = (f16)x;
        f16 l = (f16)((x - (float)h) * LO_SCALE);
        Th[(size_t)(bx + r) * 512 + by + lx] = h;
        Tl[(size_t)(bx + r) * 512 + by + lx] = l;
    }
}

// ---------------------------------------------------------------------------
// Split-fp16 MFMA GEMM, A fp32 (in-kernel split): V projection only
// (selection-irrelevant).  mode 1 = fp32 head-split write.
// ---------------------------------------------------------------------------
__global__ __launch_bounds__(256)
void gemm_x32(const float* __restrict__ X,
              const f16* __restrict__ Bh_, const f16* __restrict__ Bl_,
              const float* __restrict__ bias, float* __restrict__ outF, int mode)
{
    __shared__ f16 sm[16384];
    f16* As_h = sm;       f16* As_l = sm + 4096;
    f16* Bs_h = sm + 8192; f16* Bs_l = sm + 12288;
    const int tid  = threadIdx.x;
    const int lane = tid & 63, wv = tid >> 6;
    const int wm = wv & 1, wn = wv >> 1;
    const int quad = lane >> 4, l15 = lane & 15;
    const int m0 = blockIdx.y * 128, n0 = blockIdx.x * 128;

    floatx4 acc_h[4][4], acc_c[4][4];
    const floatx4 z4 = {0.f, 0.f, 0.f, 0.f};
#pragma unroll
    for (int i = 0; i < 4; ++i)
#pragma unroll
        for (int j = 0; j < 4; ++j) { acc_h[i][j] = z4; acc_c[i][j] = z4; }

    for (int k0 = 0; k0 < 512; k0 += 32) {
        __syncthreads();
#pragma unroll
        for (int c = 0; c < 4; ++c) {
            int r   = c * 32 + (tid >> 3);
            int col = (tid & 7) * 4;
            f32x4 x = *(const f32x4*)(X + (size_t)(m0 + r) * 512 + k0 + col);
            f16 h0 = (f16)x.x, h1 = (f16)x.y, h2 = (f16)x.z, h3 = (f16)x.w;
            half4 hv = {h0, h1, h2, h3};
            half4 lv = {(f16)((x.x - (float)h0) * LO_SCALE),
                        (f16)((x.y - (float)h1) * LO_SCALE),
                        (f16)((x.z - (float)h2) * LO_SCALE),
                        (f16)((x.w - (float)h3) * LO_SCALE)};
            *(half4*)&As_h[r * 32 + col] = hv;
            *(half4*)&As_l[r * 32 + col] = lv;
        }
#pragma unroll
        for (int c = 0; c < 2; ++c) {
            int r    = c * 64 + (wv << 4) + (lane >> 2);
            int ch   = (lane & 3) * 8;
            int lidx = (c * 64 + (wv << 4)) * 32 + lane * 8;
            gl_lds16(Bh_ + (size_t)(n0 + r) * 512 + k0 + ch, &Bs_h[lidx]);
            gl_lds16(Bl_ + (size_t)(n0 + r) * 512 + k0 + ch, &Bs_l[lidx]);
        }
        asm volatile("s_waitcnt vmcnt(0)" ::: "memory");
        __syncthreads();

        half8 bh8[4], bl8[4];
#pragma unroll
        for (int j = 0; j < 4; ++j) {
            int n = wn * 64 + j * 16 + l15;
            bh8[j] = *(const half8*)&Bs_h[n * 32 + quad * 8];
            bl8[j] = *(const half8*)&Bs_l[n * 32 + quad * 8];
        }
#pragma unroll
        for (int i = 0; i < 4; ++i) {
            int m = wm * 64 + i * 16 + l15;
            half8 ah = *(const half8*)&As_h[m * 32 + quad * 8];
            half8 al = *(const half8*)&As_l[m * 32 + quad * 8];
#pragma unroll
            for (int j = 0; j < 4; ++j) {
                acc_h[i][j] = __builtin_amdgcn_mfma_f32_16x16x32_f16(ah, bh8[j], acc_h[i][j], 0, 0, 0);
                acc_c[i][j] = __builtin_amdgcn_mfma_f32_16x16x32_f16(ah, bl8[j], acc_c[i][j], 0, 0, 0);
                acc_c[i][j] = __builtin_amdgcn_mfma_f32_16x16x32_f16(al, bh8[j], acc_c[i][j], 0, 0, 0);
            }
        }
    }

#pragma unroll
    for (int j = 0; j < 4; ++j) {
        int col = n0 + wn * 64 + j * 16 + l15;
        float bv = bias[col];
#pragma unroll
        for (int i = 0; i < 4; ++i) {
            int rbase = m0 + wm * 64 + i * 16 + quad * 4;
#pragma unroll
            for (int rg = 0; rg < 4; ++rg) {
                float r = acc_h[i][j][rg] + acc_c[i][j][rg] * INV_LO + bv;
                int row = rbase + rg;
                if (mode == 2) {
                    outF[(size_t)row * 512 + col] = r;
                } else {
                    int b_ = row >> 11, s = row & 2047, h = col >> 6, d = col & 63;
                    outF[(((size_t)(b_ * NH + h)) * S_LEN + s) * DH + d] = r;
                }
            }
        }
    }
}

// ---------------------------------------------------------------------------
// Split-fp16 MFMA GEMM, both operands pre-split planes [row][k].
// mode 2: out-proj (K=512, C = A@B^T + bias, fp32 [8192][512]).
// ---------------------------------------------------------------------------
__global__ __launch_bounds__(256)
void gemm_x16(const f16* __restrict__ Ah_, const f16* __restrict__ Al_,
              const f16* __restrict__ Bh_, const f16* __restrict__ Bl_,
              const float* __restrict__ bias, float* __restrict__ outF,
              int Ksz, int ldc, int mode)
{
    __shared__ f16 sm[16384];
    f16* As_h = sm;        f16* As_l = sm + 4096;
    f16* Bs_h = sm + 8192; f16* Bs_l = sm + 12288;
    const int tid  = threadIdx.x;
    const int lane = tid & 63, wv = tid >> 6;
    const int wm = wv & 1, wn = wv >> 1;
    const int quad = lane >> 4, l15 = lane & 15;
    const int m0 = blockIdx.y * 128, n0 = blockIdx.x * 128;

    floatx4 acc_h[4][4], acc_c[4][4];
    const floatx4 z4 = {0.f, 0.f, 0.f, 0.f};
#pragma unroll
    for (int i = 0; i < 4; ++i)
#pragma unroll
        for (int j = 0; j < 4; ++j) { acc_h[i][j] = z4; acc_c[i][j] = z4; }

    for (int k0 = 0; k0 < Ksz; k0 += 32) {
        __syncthreads();
#pragma unroll
        for (int c = 0; c < 2; ++c) {
            int r    = c * 64 + (wv << 4) + (lane >> 2);
            int ch   = (lane & 3) * 8;
            int lidx = (c * 64 + (wv << 4)) * 32 + lane * 8;
            gl_lds16(Ah_ + (size_t)(m0 + r) * Ksz + k0 + ch, &As_h[lidx]);
            gl_lds16(Al_ + (size_t)(m0 + r) * Ksz + k0 + ch, &As_l[lidx]);
            gl_lds16(Bh_ + (size_t)(n0 + r) * Ksz + k0 + ch, &Bs_h[lidx]);
            gl_lds16(Bl_ + (size_t)(n0 + r) * Ksz + k0 + ch, &Bs_l[lidx]);
        }
        asm volatile("s_waitcnt vmcnt(0)" ::: "memory");
        __syncthreads();

        half8 bh8[4], bl8[4];
#pragma unroll
        for (int j = 0; j < 4; ++j) {
            int n = wn * 64 + j * 16 + l15;
            bh8[j] = *(const half8*)&Bs_h[n * 32 + quad * 8];
            bl8[j] = *(const half8*)&Bs_l[n * 32 + quad * 8];
        }
#pragma unroll
        for (int i = 0; i < 4; ++i) {
            int m = wm * 64 + i * 16 + l15;
            half8 ah = *(const half8*)&As_h[m * 32 + quad * 8];
            half8 al = *(const half8*)&As_l[m * 32 + quad * 8];
#pragma unroll
            for (int j = 0; j < 4; ++j) {
                acc_h[i][j] = __builtin_amdgcn_mfma_f32_16x16x32_f16(ah, bh8[j], acc_h[i][j], 0, 0, 0);
                acc_c[i][j] = __builtin_amdgcn_mfma_f32_16x16x32_f16(ah, bl8[j], acc_c[i][j], 0, 0, 0);
                acc_c[i][j] = __builtin_amdgcn_mfma_f32_16x16x32_f16(al, bh8[j], acc_c[i][j], 0, 0, 0);
            }
        }
    }

#pragma unroll
    for (int j = 0; j < 4; ++j) {
        int col = n0 + wn * 64 + j * 16 + l15;
        float bv = (mode == 2) ? bias[col] : 0.f;
#pragma unroll
        for (int i = 0; i < 4; ++i) {
            int rbase = m0 + wm * 64 + i * 16 + quad * 4;
#pragma unroll
            for (int rg = 0; rg < 4; ++rg) {
                float r = acc_h[i][j][rg] + acc_c[i][j][rg] * INV_LO;
                int row = rbase + rg;
                outF[(size_t)row * ldc + col] = r + bv;
            }
        }
    }
}

// ---------------------------------------------------------------------------
// Top-k + renorm + sparse attention.  One wave per query row.  All LDS
// state is wave-private ([wv]) -> inter-wave __syncthreads replaced by
// wave-local lgkmcnt fences (waves proceed independently).  NT loads for
// the read-once logits, NT stores for the w row.  Selection semantics
// identical to the R5-passing kernel.
// ---------------------------------------------------------------------------
__device__ __forceinline__ unsigned sortable_u(float f) {
    unsigned u = __float_as_uint(f);
    return u ^ ((unsigned)(((int)u) >> 31) | 0x80000000u);
}

__global__ __launch_bounds__(256)
void topk_attn(float* __restrict__ wbuf, const float* __restrict__ Vh,
               f16* __restrict__ attH, f16* __restrict__ attL)
{
    __shared__ float    wrow[4][2048];
    __shared__ uint64_t cand[4][CMAX];
    __shared__ float    win_w[4][TOPK];
    __shared__ int      win_i[4][TOPK];

    const int tid  = threadIdx.x;
    const int wv   = tid >> 6;
    const int lane = tid & 63;
    const unsigned long long lt = (1ull << lane) - 1ull;
    const int row = blockIdx.x * 4 + wv;        // (b*8+h)*2048 + s
    float* wr = wbuf + (size_t)row * 2048;

    if (lane < TOPK) { win_w[wv][lane] = 0.f; win_i[wv][lane] = 0; }

    float L[32];
#pragma unroll
    for (int t = 0; t < 8; ++t) {
        f32x4 x = __builtin_nontemporal_load((const f32x4*)(wr + t * 256 + lane * 4));
        L[4 * t + 0] = x.x; L[4 * t + 1] = x.y; L[4 * t + 2] = x.z; L[4 * t + 3] = x.w;
    }

    // zero own w row early (wave-private; ordered vs later scatter by fence)
    const f32x4 z = {0.f, 0.f, 0.f, 0.f};
#pragma unroll
    for (int t = 0; t < 8; ++t) ((f32x4*)wrow[wv])[t * 64 + lane] = z;

    float m = L[0];
#pragma unroll
    for (int t = 1; t < 32; ++t) m = fmaxf(m, L[t]);
#pragma unroll
    for (int off = 32; off > 0; off >>= 1) m = fmaxf(m, __shfl_xor(m, off, 64));

    auto wcount = [&](float T) -> int {
        int c = 0;
#pragma unroll
        for (int t = 0; t < 32; ++t) c += (int)__popcll(__ballot(L[t] >= T));
        return c;                    // wave-uniform
    };

    // threshold Tlo with 32 <= count(l >= Tlo), narrowed until count <= 64
    float delta = 2.f;
    int clo = wcount(m - delta);
    int guard = 0;
    while (clo < TOPK && guard < 8) { delta *= 16.f; clo = wcount(m - delta); ++guard; }
    float Tlo = m - delta, Thi = m;
    guard = 0;
    while (clo > 64 && guard < 40) {
        float mid = 0.5f * (Tlo + Thi);
        int cc = wcount(mid);
        if (cc >= TOPK) { Tlo = mid; clo = cc; } else { Thi = mid; }
        ++guard;
    }
    const int nc = min(clo, CMAX);

    // compact candidates as packed sortable keys (value desc, index asc)
    int base = 0;
#pragma unroll
    for (int t = 0; t < 32; ++t) {
        bool p = (L[t] >= Tlo);
        unsigned long long mk = __ballot(p);
        if (p) {
            int pos = base + (int)__popcll(mk & lt);
            if (pos < CMAX) {
                int idx = (t >> 2) * 256 + (lane << 2) + (t & 3);
                cand[wv][pos] = ((uint64_t)sortable_u(L[t]) << 32) | (uint32_t)(~(uint32_t)idx);
            }
        }
        base += (int)__popcll(mk);
    }
    lds_fence();

    // exact rank: winners = rank < 32 (u64 compare handles tie-break)
    float mysum = 0.f;
    int wbase = 0;
    const int passes = (nc + 63) >> 6;
    for (int it = 0; it < passes; ++it) {
        int ci = (it << 6) + lane;
        bool have = ci < nc;
        uint64_t mykey = have ? cand[wv][ci] : 0ull;
        int rank = 0;
#pragma unroll 8
        for (int j = 0; j < nc; ++j)
            rank += (cand[wv][j] > mykey) ? 1 : 0;
        bool win = have && (rank < TOPK);
        unsigned long long mk = __ballot(win);
        if (win) {
            int pos = wbase + (int)__popcll(mk & lt);
            unsigned uv = (unsigned)(mykey >> 32);
            unsigned fu = (uv & 0x80000000u) ? (uv ^ 0x80000000u) : ~uv;
            float v = __uint_as_float(fu);
            int idx = (int)(~(uint32_t)mykey);
            float e = __expf(v - m);
            win_w[wv][pos] = e;
            win_i[wv][pos] = idx;
            mysum += e;
        }
        wbase += (int)__popcll(mk);
    }
#pragma unroll
    for (int off = 32; off > 0; off >>= 1) mysum += __shfl_xor(mysum, off, 64);
    const float rw = 1.f / mysum;
    lds_fence();

    // scatter winners into own zeroed row
    if (lane < TOPK) wrow[wv][win_i[wv][lane] & 2047] = win_w[wv][lane] * rw;
    lds_fence();

    // stream the sparse w row out with NT stores
#pragma unroll
    for (int t = 0; t < 8; ++t)
        __builtin_nontemporal_store(((f32x4*)wrow[wv])[t * 64 + lane],
                                    (f32x4*)(wr + (size_t)(t * 64 + lane) * 4));

    // sparse attention: 32 weighted V rows; lane = head-dim index
    const int bh = row >> 11;
    const float* Vb = Vh + (size_t)bh * S_LEN * DH;
    float acc = 0.f;
#pragma unroll
    for (int j = 0; j < TOPK; ++j) {
        float wj = win_w[wv][j] * rw;
        int   kj = win_i[wv][j];
        acc = fmaf(wj, Vb[(size_t)kj * DH + lane], acc);
    }
    const int b_ = row >> 14;
    const int h  = (row >> 11) & 7;
    const int s  = row & 2047;
    size_t oidx = (((size_t)b_ * S_LEN) + s) * 512 + h * DH + lane;
    f16 hh = (f16)acc;
    attH[oidx] = hh;
    attL[oidx] = (f16)((acc - (float)hh) * LO_SCALE);
}

// ---------------------------------------------------------------------------
extern "C" void kernel_launch(void* const* d_in, const int* in_sizes, int n_in,
                              void* d_out, int out_size, void* d_ws, size_t ws_size,
                              hipStream_t stream) {
    const float* v  = (const float*)d_in[0];
    const float* k  = (const float*)d_in[1];
    const float* q  = (const float*)d_in[2];
    const float* Wq = (const float*)d_in[3];
    const float* bq = (const float*)d_in[4];
    const float* Wk = (const float*)d_in[5];
    const float* bk = (const float*)d_in[6];
    const float* Wv = (const float*)d_in[7];
    const float* bv = (const float*)d_in[8];
    const float* Wo = (const float*)d_in[9];
    const float* bo = (const float*)d_in[10];

    float* out  = (float*)d_out;                    // [4,2048,512]
    float* wout = out + (size_t)4 * S_LEN * 512;    // [4,8,2048,2048] (logits scratch, then w)

    char* ws = (char*)d_ws;
    float* Vh   = (float*)ws;                       // fp32 [B,H,S,dh], 16 MB
    float* Qh32 = (float*)(ws + 16777216);          // fp32 [B,H,S,dh], 16 MB
    float* Kh32 = (float*)(ws + 33554432);          // fp32 [B,H,S,dh], 16 MB
    f16* WT  = (f16*)(ws + 50331648);               // 4 planes of 512x512, 2 MB
    f16 *WvH = WT,           *WvL = WT + 262144;
    f16 *WoH = WT + 524288,  *WoL = WT + 786432;
    // att planes alias Qh32 (dead after gemm_logits): 8 MB + 8 MB
    f16* attH = (f16*)(ws + 16777216);
    f16* attL = (f16*)(ws + 25165824);

    wsplit2<<<dim3(16, 16, 2), 256, 0, stream>>>(Wv, Wo, WT);

    qkproj<<<dim3(4, 64, 2), 256, 0, stream>>>(q, k, Wq, Wk, bq, bk, Qh32, Kh32);
    gemm_x32<<<dim3(4, 64), 256, 0, stream>>>(v, WvH, WvL, bv, Vh, 1);

    gemm_logits<<<dim3(16, 16, 32), 256, 0, stream>>>(Qh32, Kh32, wout);

    topk_attn<<<16384, 256, 0, stream>>>(wout, Vh, attH, attL);

    gemm_x16<<<dim3(4, 64, 1), 256, 0, stream>>>(attH, attL, WoH, WoL, bo, out, 512, 512, 2);
}